// Round 1
// baseline (1906.620 us; speedup 1.0000x reference)
//
#include <hip/hip_runtime.h>
#include <math.h>

// Problem constants
#define Nn     2048
#define NEc    32768
#define ETc    4
#define NEDGE  (ETc * NEc)     // 131072
#define FS     68              // padded feature stride (66 used)
#define HIDc   128
#define GSZ    512             // 4*HID

// ---------------- workspace layout (offsets in 4-byte units) ----------------
#define O_COEFF   0L
#define O_COUNTS  (O_COEFF  + 32L)
#define O_OFFS    (O_COUNTS + 2048L)
#define O_CURSOR  (O_OFFS   + 2052L)
#define O_PACKED  (O_CURSOR + 2048L)
#define O_VALS    (O_PACKED + 131072L)
#define O_U       (O_VALS   + 131072L)              // 2048*68
#define O_V       (O_U      + 139264L)              // 2 ch * 2048*68
#define O_T       (O_V      + 278528L)
#define O_S       (O_T      + 278528L)
#define O_X       (O_S      + 278528L)              // 2048*128
#define O_G       (O_X      + 262144L)              // 2048*512
#define O_HS      (O_G      + 1048576L)             // 2048*128
// total ~2.82M floats = ~11.3 MB

__device__ __forceinline__ float sigmoid_f(float x) {
    float e = __expf(-x);
    return 1.0f / (1.0f + e);
}
__device__ __forceinline__ float tanh_f(float x) {
    // tanh(x) = 1 - 2/(e^{2x}+1); graceful at +-inf
    float e = __expf(2.0f * x);
    return 1.0f - 2.0f / (e + 1.0f);
}

// ---- softmax coefficients: coeff[(l*2+c)*4 + e] = softmax(gt_w[l][c][:])[e]
__global__ void coeff_kernel(const float* __restrict__ gtw, float* __restrict__ coeff) {
    int t = threadIdx.x;
    if (t < 6) {
        const float* w = gtw + t * 4;
        float m = fmaxf(fmaxf(w[0], w[1]), fmaxf(w[2], w[3]));
        float e0 = expf(w[0] - m), e1 = expf(w[1] - m);
        float e2 = expf(w[2] - m), e3 = expf(w[3] - m);
        float s = ((e0 + e1) + e2) + e3;
        float r = 1.0f / s;
        coeff[t * 4 + 0] = e0 * r;
        coeff[t * 4 + 1] = e1 * r;
        coeff[t * 4 + 2] = e2 * r;
        coeff[t * 4 + 3] = e3 * r;
    }
}

// ---- CSR build: count per row
__global__ void count_kernel(const int* __restrict__ ei, int* __restrict__ counts) {
    int e = blockIdx.x * 256 + threadIdx.x;          // 0..131071
    int t = e >> 15, k = e & 32767;
    int row = ei[t * 65536 + k];
    atomicAdd(&counts[row], 1);
}

// ---- exclusive scan over 2048 counts (single block, Hillis-Steele)
__global__ __launch_bounds__(1024) void scan_kernel(const int* __restrict__ counts,
                                                    int* __restrict__ offs,
                                                    int* __restrict__ cursor) {
    __shared__ int buf[2][2048];
    int t = threadIdx.x;
    buf[0][t]        = counts[t];
    buf[0][t + 1024] = counts[t + 1024];
    __syncthreads();
    int p = 0;
    for (int off = 1; off < 2048; off <<= 1) {
        for (int i = t; i < 2048; i += 1024) {
            int v = buf[p][i];
            if (i >= off) v += buf[p][i - off];
            buf[p ^ 1][i] = v;
        }
        __syncthreads();
        p ^= 1;
    }
    for (int i = t; i < 2048; i += 1024) {
        int inc = buf[p][i];
        offs[i + 1] = inc;
        int ex = inc - counts[i];
        cursor[i] = ex;
    }
    if (t == 0) offs[0] = 0;
}

// ---- scatter edges into CSR slots (etype packed in high bits of col word)
__global__ void scatter_kernel(const int* __restrict__ ei, const float* __restrict__ ev,
                               int* __restrict__ cursor, int* __restrict__ packed,
                               float* __restrict__ vals) {
    int e = blockIdx.x * 256 + threadIdx.x;
    int t = e >> 15, k = e & 32767;
    int row = ei[t * 65536 + k];
    int col = ei[t * 65536 + 32768 + k];
    float v = ev[t * 32768 + k];
    int slot = atomicAdd(&cursor[row], 1);
    packed[slot] = col | (t << 16);
    vals[slot] = v;
}

// ---- XW = X @ W_gcn, assemble U = [XW | 1 | 0 | pad]
__global__ void xw_kernel(const float* __restrict__ X, const float* __restrict__ Wg,
                          float* __restrict__ U) {
    __shared__ float Wl[64][65];
    __shared__ float Xl[16][64];
    int tid = threadIdx.x;                            // 256 threads
    for (int i = tid; i < 4096; i += 256) Wl[i >> 6][i & 63] = Wg[i];
    int r0 = blockIdx.x * 16;
    for (int i = tid; i < 1024; i += 256) Xl[i >> 6][i & 63] = X[r0 * 64 + i];
    __syncthreads();
    int lane = tid & 63, wv = tid >> 6;
    for (int rr = wv; rr < 16; rr += 4) {
        float acc = 0.0f;
        #pragma unroll
        for (int k = 0; k < 64; ++k) acc += Xl[rr][k] * Wl[k][lane];
        long r = r0 + rr;
        U[r * FS + lane] = acc;
        if (lane == 0) {
            U[r * FS + 64] = 1.0f;   // ones column (carries deg chains)
            U[r * FS + 65] = 0.0f;
            U[r * FS + 66] = 0.0f;
            U[r * FS + 67] = 0.0f;
        }
    }
}

// ---- SpMM: out_c[row, :] = sum_e coeff[layer][c][etype]*val * in_c[col, :]
// one wave per (row); grid = (2048, C). cols 0..63 -> lane; cols 64,65 -> lanes 0,1.
__global__ __launch_bounds__(64) void spmm_kernel(
    const int* __restrict__ offs, const int* __restrict__ packed,
    const float* __restrict__ vals, const float* __restrict__ coeff, int layer,
    const float* __restrict__ in, long in_ch_stride,
    float* __restrict__ out, long out_ch_stride, int append_one) {
    __shared__ float cl[4];
    int c = blockIdx.y;
    int lane = threadIdx.x;
    if (lane < 4) cl[lane] = coeff[(layer * 2 + c) * 4 + lane];
    __syncthreads();
    int row = blockIdx.x;
    const float* inc = in + (long)c * in_ch_stride;
    float* outc = out + (long)c * out_ch_stride;
    int s = offs[row], e = offs[row + 1];
    float acc = 0.0f, accb = 0.0f;
    for (int i = s; i < e; ++i) {
        int pc = packed[i];
        float v = vals[i];
        long col = pc & 0xFFFF;
        float w = cl[pc >> 16] * v;
        acc += w * inc[col * FS + lane];
        if (lane < 2) accb += w * inc[col * FS + 64 + lane];
    }
    outc[(long)row * FS + lane] = acc;
    if (lane < 2) {
        float vb = accb;
        if (append_one && lane == 1) vb = 1.0f;       // append constant-1 column
        outc[(long)row * FS + 64 + lane] = vb;
    }
}

// ---- finalize: X_[n, c*64+f] = relu(dinv2*dinv1*S_c[n,f] + b_gcn[f])
__global__ __launch_bounds__(128) void finalize_kernel(const float* __restrict__ S,
                                                       const float* __restrict__ bg,
                                                       float* __restrict__ Xo) {
    int n = blockIdx.x;
    int tid = threadIdx.x;                            // 128
    int c = tid >> 6, f = tid & 63;
    const float* Sc = S + (long)c * 139264L + (long)n * FS;
    float deg1 = Sc[65];
    float dinv1 = (deg1 != 0.0f) ? 1.0f / deg1 : 0.0f;
    float deg2 = dinv1 * Sc[64];
    float dinv2 = (deg2 != 0.0f) ? 1.0f / deg2 : 0.0f;
    float v = dinv2 * (dinv1 * Sc[f]) + bg[f];
    Xo[(long)n * 128 + tid] = v > 0.0f ? v : 0.0f;
}

// ---- G[n, g] = X_[n,:] . W_ih[g,:] + b_ih[g] + b_hh[g]
__global__ __launch_bounds__(512) void gin_kernel(const float* __restrict__ Xi,
                                                  const float* __restrict__ Wih,
                                                  const float* __restrict__ bih,
                                                  const float* __restrict__ bhh,
                                                  float* __restrict__ G) {
    __shared__ float Xl[16][128];
    int tid = threadIdx.x;                            // 512; g = tid
    int r0 = blockIdx.x * 16;
    for (int i = tid; i < 2048; i += 512) Xl[i >> 7][i & 127] = Xi[(long)r0 * 128 + i];
    __syncthreads();
    float acc[16];
    #pragma unroll
    for (int r = 0; r < 16; ++r) acc[r] = 0.0f;
    for (int k = 0; k < 128; ++k) {
        float w = Wih[(long)tid * 128 + k];
        #pragma unroll
        for (int r = 0; r < 16; ++r) acc[r] += Xl[r][k] * w;
    }
    float b = bih[tid] + bhh[tid];
    #pragma unroll
    for (int r = 0; r < 16; ++r) G[(long)(r0 + r) * GSZ + tid] = acc[r] + b;
}

// ---- sequential LSTM: one block, 512 threads, W_hh row-per-thread in registers
__global__ __launch_bounds__(512, 2) void lstm_kernel(const float* __restrict__ Whh,
                                                      const float* __restrict__ G,
                                                      float* __restrict__ hs) {
    __shared__ __align__(16) float h_lds[128];
    __shared__ float act[512];
    int tid = threadIdx.x;
    float4 w[32];
    const float4* W4 = reinterpret_cast<const float4*>(Whh) + (long)tid * 32;
    #pragma unroll
    for (int i = 0; i < 32; ++i) w[i] = W4[i];
    if (tid < 128) h_lds[tid] = 0.0f;
    float c = 0.0f;
    __syncthreads();
    float gin = G[tid];
    const float4* h4 = reinterpret_cast<const float4*>(h_lds);
    for (int t = 0; t < Nn; ++t) {
        float gnext = (t + 1 < Nn) ? G[(long)(t + 1) * GSZ + tid] : 0.0f;
        float a0 = gin, a1 = 0.0f, a2 = 0.0f, a3 = 0.0f;
        #pragma unroll
        for (int i = 0; i < 32; ++i) {
            float4 hv = h4[i];
            float4 wv = w[i];
            a0 += wv.x * hv.x;
            a1 += wv.y * hv.y;
            a2 += wv.z * hv.z;
            a3 += wv.w * hv.w;
        }
        float g = (a0 + a1) + (a2 + a3);
        float a = ((tid >> 7) == 2) ? tanh_f(g) : sigmoid_f(g);   // i,f,o: sigmoid; g: tanh
        act[tid] = a;
        __syncthreads();
        if (tid < 128) {
            float i_ = act[tid], f_ = act[128 + tid], g_ = act[256 + tid], o_ = act[384 + tid];
            c = f_ * c + i_ * g_;
            float th = tanh_f(c);
            float h = o_ * th;
            h_lds[tid] = h;
            hs[(long)t * 128 + tid] = h;
        }
        __syncthreads();
        gin = gnext;
    }
}

// ---- y[n] = leaky_relu(hs[n,:] . W_lin + b_lin)
__global__ __launch_bounds__(256) void y_kernel(const float* __restrict__ hs,
                                                const float* __restrict__ wl,
                                                const float* __restrict__ bl,
                                                float* __restrict__ out) {
    int row = blockIdx.x * 4 + (threadIdx.x >> 6);
    int lane = threadIdx.x & 63;
    float p = hs[(long)row * 128 + lane] * wl[lane] +
              hs[(long)row * 128 + 64 + lane] * wl[64 + lane];
    #pragma unroll
    for (int off = 32; off > 0; off >>= 1) p += __shfl_down(p, off);
    if (lane == 0) {
        float y = p + bl[0];
        out[row] = (y >= 0.0f) ? y : 0.2f * y;
    }
}

extern "C" void kernel_launch(void* const* d_in, const int* in_sizes, int n_in,
                              void* d_out, int out_size, void* d_ws, size_t ws_size,
                              hipStream_t stream) {
    (void)in_sizes; (void)n_in; (void)out_size; (void)ws_size;
    const int*   ei   = (const int*)  d_in[0];   // (4,2,32768)
    const float* ev   = (const float*)d_in[1];   // (4,32768)
    const float* X    = (const float*)d_in[2];   // (2048,64)
    const float* gtw  = (const float*)d_in[4];   // (3,2,4)
    const float* Wg   = (const float*)d_in[5];   // (64,64)
    const float* bg   = (const float*)d_in[6];   // (64)
    const float* Wih  = (const float*)d_in[7];   // (512,128)
    const float* Whh  = (const float*)d_in[8];   // (512,128)
    const float* bih  = (const float*)d_in[9];
    const float* bhh  = (const float*)d_in[10];
    const float* wl   = (const float*)d_in[11];  // (1,128)
    const float* bl   = (const float*)d_in[12];
    float* out = (float*)d_out;

    float* ws = (float*)d_ws;
    float* coeff  = ws + O_COEFF;
    int*   counts = (int*)(ws + O_COUNTS);
    int*   offs   = (int*)(ws + O_OFFS);
    int*   cursor = (int*)(ws + O_CURSOR);
    int*   packed = (int*)(ws + O_PACKED);
    float* vals   = ws + O_VALS;
    float* U      = ws + O_U;
    float* V      = ws + O_V;
    float* T      = ws + O_T;
    float* S      = ws + O_S;
    float* Xf     = ws + O_X;
    float* G      = ws + O_G;
    float* hsb    = ws + O_HS;

    hipMemsetAsync(counts, 0, 2048 * sizeof(int), stream);
    coeff_kernel<<<1, 64, 0, stream>>>(gtw, coeff);
    count_kernel<<<NEDGE / 256, 256, 0, stream>>>(ei, counts);
    scan_kernel<<<1, 1024, 0, stream>>>(counts, offs, cursor);
    scatter_kernel<<<NEDGE / 256, 256, 0, stream>>>(ei, ev, cursor, packed, vals);
    xw_kernel<<<Nn / 16, 256, 0, stream>>>(X, Wg, U);
    // chain: V = A2 [XW|1], append 1-col; T = A1 V'; S = A0 T
    spmm_kernel<<<dim3(Nn, 2), 64, 0, stream>>>(offs, packed, vals, coeff, 2,
                                                U, 0L, V, 139264L, 1);
    spmm_kernel<<<dim3(Nn, 2), 64, 0, stream>>>(offs, packed, vals, coeff, 1,
                                                V, 139264L, T, 139264L, 0);
    spmm_kernel<<<dim3(Nn, 2), 64, 0, stream>>>(offs, packed, vals, coeff, 0,
                                                T, 139264L, S, 139264L, 0);
    finalize_kernel<<<Nn, 128, 0, stream>>>(S, bg, Xf);
    gin_kernel<<<Nn / 16, 512, 0, stream>>>(Xf, Wih, bih, bhh, G);
    lstm_kernel<<<1, 512, 0, stream>>>(Whh, G, hsb);
    y_kernel<<<Nn / 4, 256, 0, stream>>>(hsb, wl, bl, out);
}